// Round 6
// baseline (135.742 us; speedup 1.0000x reference)
//
#include <hip/hip_runtime.h>
#include <math.h>

// Problem constants (from reference)
#define NDIM   8
#define NBINS  64
#define LOG_BETA   (-13.815510557964274f)  // log(1e-6)
#define LN2F       0.69314718055994531f
// mesh is geometric: boundary_j (original coords) = x1L*(1.2^j-1)/0.2, j=0..32
// bin index from |x|: g = log2(1 + ALPHA*|x|) / log2(1.2);  ALPHA = (1.2^32-1)/10
#define ALPHA      34.0821892f
#define INV_LOG2R  3.80178401692393f       // 1/log2(1.2)
#define L2R        0.26303440583379378f    // log2(1.2)

typedef float f32x4 __attribute__((ext_vector_type(4)));  // ok for nontemporal builtins

// Two threads per point: lane g handles float4 half (g&1) of point (g>>1).
// R5 structure + unroll-by-2 with explicit gather/consume phase split:
// both bodies' 8 ds_read_b128 are issued before either consume phase, so one
// body's LDS-gather latency hides under the other's arithmetic (in-order
// waves expose the chain once per ITERATION, now amortized over 2 bodies).
__global__ __launch_bounds__(256, 7) void cdfq_fused(const float* __restrict__ x,
                                                     const float* __restrict__ logdet_in,
                                                     const float* __restrict__ p,
                                                     float* __restrict__ y_out,
                                                     float* __restrict__ ld_out,
                                                     int n)
{
    __shared__ float4 stbl[NDIM * NBINS];  // [d][k]: {v1, slope, F_pre, mesh_k}

    const int t  = threadIdx.x;
    const int T  = gridDim.x * blockDim.x;         // work-item stride
    const int i0 = blockIdx.x * blockDim.x + t;
    const int G  = 2 * n;                          // work items = half-points
    const int iters = G / T;                       // 8 on the bench shape
    const f32x4* xv4 = (const f32x4*)x;

    // ---- prologue: 2-deep prefetch issued BEFORE prep ----
    f32x4 X0, X1; float L0, L1;
    if (iters > 0) { X0 = xv4[i0];     L0 = logdet_in[i0 >> 1]; }
    if (iters > 1) { X1 = xv4[i0 + T]; L1 = logdet_in[(i0 + T) >> 1]; }
    __builtin_amdgcn_sched_barrier(0);   // do not sink these below prep

    // ---- prep: each wave builds TWO dims of the table fully in-register.
    //      Runs while prologue loads are in flight. ONE barrier total. ----
    {
        const int lane = t & 63;
        const int w    = t >> 6;
        const float pw32 = exp2f(32.0f * L2R);     // 1.2^32
        const float inv  = 0.5f / (pw32 - 1.0f);
        auto meshf = [&](float tt) {               // normalized mesh coordinate
            float fidx = tt - 32.0f;
            float pw = exp2f(fabsf(fidx) * L2R);
            float r  = (pw - 1.0f) * inv;
            return 0.5f + ((fidx >= 0.0f) ? r : -r);
        };
        const float m0  = meshf((float)lane);          // mesh[lane]
        const float m1  = meshf((float)(lane + 1));    // mesh[lane+1]
        const float el  = m1 - m0;                     // elmt[lane]
        const float el1 = __shfl_down(el, 1);          // elmt[lane+1] (lane63 unused)
        const float e0e63 = 2.0f * (meshf(1.0f) - meshf(0.0f)); // elmt[0]+elmt[63]

#pragma unroll
        for (int dd = 0; dd < 2; ++dd) {
            const int d = 2 * w + dd;
            float ep = 0.0f;
            if (lane < 63) ep = __expf(p[lane * NDIM + d]);  // interior node lane+1
            // normalization: sum of ep * (elmt[k]+elmt[k+1])/2 over interior nodes
            float s = ep * 0.5f * (el + el1);
#pragma unroll
            for (int off = 32; off; off >>= 1) s += __shfl_xor(s, off);
            const float scale = (1.0f - e0e63 * 5e-7f) / s;
            const float epu = __shfl_up(ep, 1);
            const float pdl = (lane == 0)  ? 1e-6f : scale * epu;  // pdf[lane]
            const float pdn = (lane == 63) ? 1e-6f : scale * ep;   // pdf[lane+1]
            const float cell = 0.5f * (pdl + pdn) * el;
            // inclusive scan -> exclusive prefix
            float v = cell;
#pragma unroll
            for (int off = 1; off < 64; off <<= 1) {
                float u = __shfl_up(v, off);
                if (lane >= off) v += u;
            }
            stbl[(d << 6) | lane] = make_float4(pdl, (pdn - pdl) / el, v - cell, m0);
        }
    }
    __syncthreads();

    // ---- iteration-invariant hoists: half-point parity never changes ----
    const float4* tbl = &stbl[((i0 & 1) << 2) << 6];   // dims 0-3 or 4-7 base
    const bool evenlane = ((i0 & 1) == 0);

    // ---- phase A: bin-index + table gather (issues 4 ds_read_b128) ----
    auto gatherA = [&](f32x4 Xv, f32x4* tb) {
#pragma unroll
        for (int dl = 0; dl < 4; ++dl) {
            float xo = Xv[dl];
            // analytic bin: g = log2(1 + alpha*|x|)/log2(1.2); one v_log_f32
            float gg = __log2f(fmaf(ALPHA, fabsf(xo), 1.0f)) * INV_LOG2R;
            // merged index (CDF & dCDF continuous at bin boundaries):
            // jf in [0,31] -> 32+jf == 32^jf, 31-jf == 31^jf: one cndmask + xor
            int jf = (int)fminf(gg, 31.0f);
            int k  = ((xo >= 0.0f) ? 32 : 31) ^ jf;
            tb[dl] = *(const f32x4*)&tbl[(dl << 6) + k]; // {v1, slope, F_pre, mesh_k}
        }
    };

    // ---- phase B: consume gathered entries, fold logdet, store ----
    auto consumeB = [&](f32x4 Xv, const f32x4* tb, float Lin, int g) {
        float yd[4], dd4[4];
        float extra = 0.0f;
#pragma unroll
        for (int dl = 0; dl < 4; ++dl) {
            float xo = Xv[dl];
            float xs = fmaf(xo, 0.05f, 0.5f);        // (x+10)/20 to 1 ulp
            f32x4 tv = tb[dl];
            float xm = xs - tv[3];
            bool cov = (fabsf(xo) < 10.0f);          // == (0 <= xs < 1)

            float yc = fmaf(xm, fmaf(0.5f * xm, tv[1], tv[0]), tv[2]);
            float dv = fmaf(xm, tv[1], tv[0]);
            float yy = cov ? yc : xs;
            dd4[dl]  = cov ? dv : 1.0f;

            yy = fmaf(yy, 20.0f, -10.0f);
            if (yy > 10.0f)  { yy = fmaf(1e-6f, yy - 10.0f, 10.0f);  extra += LOG_BETA; }
            if (yy < -10.0f) { yy = fmaf(1e-6f, yy + 10.0f, -10.0f); extra += LOG_BETA; }
            yd[dl] = yy;
        }
        // 2 x v_log_f32 of pairwise products (each product >= 1e-12, no underflow)
        float l2 = __log2f(dd4[0] * dd4[1]) + __log2f(dd4[2] * dd4[3]);
        float contrib = fmaf(l2, LN2F, extra);
        float cross   = __shfl_xor(contrib, 1);      // partner half-point

        f32x4 yv = { yd[0], yd[1], yd[2], yd[3] };
        __builtin_nontemporal_store(yv, (f32x4*)y_out + g);
        if (evenlane)
            __builtin_nontemporal_store(Lin + contrib + cross, ld_out + (g >> 1));
    };

    // ---- main loop: unrolled x2, both gathers issued before either consume ----
    int j = 0;
    for (; j + 1 < iters; j += 2) {
        f32x4 X2, X3; float L2, L3;
        const bool m2 = (j + 2 < iters), m3 = (j + 3 < iters);  // wave-uniform
        if (m2) { X2 = xv4[i0 + (j + 2) * T]; L2 = logdet_in[(i0 + (j + 2) * T) >> 1]; }
        if (m3) { X3 = xv4[i0 + (j + 3) * T]; L3 = logdet_in[(i0 + (j + 3) * T) >> 1]; }
        __builtin_amdgcn_sched_barrier(0);           // keep prefetch above compute

        f32x4 tb0[4], tb1[4];
        gatherA(X0, tb0);                            // 4 ds_read_b128 in flight
        gatherA(X1, tb1);                            // 8 ds_read_b128 in flight
        consumeB(X0, tb0, L0, i0 + j * T);           // overlaps tb1's latency
        consumeB(X1, tb1, L1, i0 + (j + 1) * T);

        if (m2) { X0 = X2; L0 = L2; }
        if (m3) { X1 = X3; L1 = L3; }
    }
    // odd-iters tail (never runs on the bench shape)
    for (; j < iters; ++j) {
        f32x4 tb0[4];
        gatherA(X0, tb0);
        consumeB(X0, tb0, L0, i0 + j * T);
        X0 = X1; L0 = L1;
    }
    // remainder (T does not divide G; never runs on the bench shape).
    // G is even and pairs are adjacent lanes, so partners enter together.
    for (int g = i0 + iters * T; g < G; g += T) {
        f32x4 Xr = xv4[g]; float Lr = logdet_in[g >> 1];
        f32x4 tbr[4];
        gatherA(Xr, tbr);
        consumeB(Xr, tbr, Lr, g);
    }
}

extern "C" void kernel_launch(void* const* d_in, const int* in_sizes, int n_in,
                              void* d_out, int out_size, void* d_ws, size_t ws_size,
                              hipStream_t stream) {
    const float* x      = (const float*)d_in[0];   // [N, 8]
    const float* logdet = (const float*)d_in[1];   // [N, 1]
    const float* p      = (const float*)d_in[2];   // [63, 8]

    const int n = in_sizes[1];                     // N points
    float* y_out  = (float*)d_out;                 // [N*8]
    float* ld_out = (float*)d_out + (size_t)n * NDIM;  // [N]

    const int block = 256;
    int grid = 2048;                               // 8 blocks/CU co-resident
    if ((long long)grid * block > 2LL * n) grid = (2 * n + block - 1) / block;
    cdfq_fused<<<grid, block, 0, stream>>>(x, logdet, p, y_out, ld_out, n);
}